// Round 20
// baseline (176.219 us; speedup 1.0000x reference)
//
#include <hip/hip_runtime.h>
#include <math.h>

// Problem dims (from reference): B=4, C=64, T=16, H=128, W=128, fp32.
#define BB 4
#define CC 64
#define TT 16
#define HH 128
#define WW 128
#define HW (HH*WW)

typedef float f32x4 __attribute__((ext_vector_type(4)));

__device__ __forceinline__ float softplus_f(float x) {
    return (x > 20.0f) ? x : log1pf(expf(x));
}

__device__ __forceinline__ float4 splat4(float v) { return make_float4(v, v, v, v); }

// float4 cross-lane fetch within a 32-lane row segment (ds_bpermute x4).
__device__ __forceinline__ float4 shfl4(float4 v, int src) {
    float4 r;
    r.x = __shfl(v.x, src, 32);
    r.y = __shfl(v.y, src, 32);
    r.z = __shfl(v.z, src, 32);
    r.w = __shfl(v.w, src, 32);
    return r;
}

// Band-size series endpoint: FULL-PLANE bands, free-running.
//   32-row bands (R11, 1024 blk x 256 thr): 101.2us
//   64-row bands (R19,  512 blk x 512 thr):  99.0us  <- FETCH unchanged;
//     win came from fewer streams + more intra-block halo (L2 tap hits)
//   128-row bands (this, 256 blk x 1024 thr): all d=+-16 taps intra-block,
//     zero cross-block vertical halo, 256 streams. Same 16 waves/CU.
// This is R15 WITHOUT the barrier that poisoned it (R15: +barrier = 165us;
// barriers/staging/prefetch all regressed across rounds 12-18 -- waves
// must free-run).
//  - NO LDS, NO barriers, NO prefetch, NO batching
//  - thread owns 4 stacked rows; d=1 vertical taps from own registers
//  - horizontal taps via lane shuffles; temporal history in registers
//  - NT stores: output never re-read
//  - plain __launch_bounds__(1024): ",N" variants pinned VGPR and spilled
__global__ __launch_bounds__(1024) void lap_st_kernel(
    const float* __restrict__ u,
    const float* __restrict__ Ds,   // (3, 64)
    const float* __restrict__ Dt,   // (2, 64)
    float* __restrict__ out)
{
    const int bc   = blockIdx.x;           // b*C + c (stack id)
    const int c    = bc & (CC - 1);
    const int tid  = threadIdx.x;
    const int jj   = tid >> 5;             // 0..31 : row group
    const int colc = tid & 31;             // chunk column (lane in row segment)
    const int col  = colc << 2;
    const int r0   = jj << 2;              // first of 4 owned rows, 0..124

    const float cs0 = softplus_f(Ds[0 * CC + c]);
    const float cs1 = softplus_f(Ds[1 * CC + c]);
    const float cs2 = softplus_f(Ds[2 * CC + c]);
    const float ct0 = softplus_f(Dt[0 * CC + c]);
    const float ct1 = softplus_f(Dt[1 * CC + c]);
    const float cu = -4.0f * (cs0 + cs1 + cs2) - (ct0 + ct1);

    const size_t bc_off = (size_t)bc * TT * HW;

    float4 pm1[4], pm2[4];

    #pragma unroll 1
    for (int t = 0; t < TT; ++t) {
        const float* __restrict__ up = u + bc_off + (size_t)t * HW;
        f32x4* outp = (f32x4*)(out + bc_off + (size_t)t * HW);

        // center rows (registers; feed +-1 taps, horizontals via shuffle,
        // and the temporal rotate)
        float4 c0[4];
        #pragma unroll
        for (int q = 0; q < 4; ++q)
            c0[q] = *(const float4*)(up + (r0 + q) * WW + col);

        if (t == 0) {   // causal clamp: u[-1] = u[-2] = u[0]
            #pragma unroll
            for (int q = 0; q < 4; ++q) { pm1[q] = c0[q]; pm2[q] = c0[q]; }
        }

        // shared boundary rows (serve +-1 taps of edge q and +-4 taps)
        const int rm1 = (r0 - 1 < 0) ? 0 : r0 - 1;
        const int rp4 = (r0 + 4 > HH - 1) ? HH - 1 : r0 + 4;
        const float4 vm1 = *(const float4*)(up + rm1 * WW + col);
        const float4 vp4 = *(const float4*)(up + rp4 * WW + col);

        #pragma unroll
        for (int q = 0; q < 4; ++q) {
            const int r = r0 + q;

            // ---- vertical taps (register reuse for d=1; clamped loads) ----
            const float4 vu1 = (q == 0) ? vm1 : c0[q - 1];
            const float4 vd1 = (q == 3) ? vp4 : c0[q + 1];
            float4 vu4, vd4;
            if (q == 3) vu4 = vm1;                       // r-4 == r0-1
            else { int rr = r - 4; rr = rr < 0 ? 0 : rr;
                   vu4 = *(const float4*)(up + rr * WW + col); }
            if (q == 0) vd4 = vp4;                       // r+4 == r0+4
            else { int rr = r + 4; rr = rr > HH - 1 ? HH - 1 : rr;
                   vd4 = *(const float4*)(up + rr * WW + col); }
            int ru16 = r - 16; ru16 = ru16 < 0 ? 0 : ru16;
            int rd16 = r + 16; rd16 = rd16 > HH - 1 ? HH - 1 : rd16;
            const float4 vu16 = *(const float4*)(up + ru16 * WW + col);
            const float4 vd16 = *(const float4*)(up + rd16 * WW + col);

            const float4 cc = c0[q];

            // ---- horizontal taps from adjacent lanes' registers ----
            const float4 L4  = shfl4(cc, colc - 1);
            const float4 R4  = shfl4(cc, colc + 1);
            const float4 L16 = shfl4(cc, colc - 4);
            const float4 R16 = shfl4(cc, colc + 4);
            const float e0   = __shfl(cc.x, 0, 32);    // row elem 0
            const float e127 = __shfl(cc.w, 31, 32);   // row elem 127
            const float4 l4  = (colc >= 1)  ? L4  : splat4(e0);
            const float4 r4  = (colc <= 30) ? R4  : splat4(e127);
            const float4 l16 = (colc >= 4)  ? L16 : splat4(e0);
            const float4 r16 = (colc <= 27) ? R16 : splat4(e127);

            const float4 p1 = pm1[q];
            const float4 p2 = pm2[q];

            f32x4 o;
            o.x = cs0 * (vu1.x + vd1.x + l4.w + cc.y)
                + cs1 * (vu4.x + vd4.x + l4.x + r4.x)
                + cs2 * (vu16.x + vd16.x + l16.x + r16.x)
                + cu * cc.x + ct0 * p1.x + ct1 * p2.x;
            o.y = cs0 * (vu1.y + vd1.y + cc.x + cc.z)
                + cs1 * (vu4.y + vd4.y + l4.y + r4.y)
                + cs2 * (vu16.y + vd16.y + l16.y + r16.y)
                + cu * cc.y + ct0 * p1.y + ct1 * p2.y;
            o.z = cs0 * (vu1.z + vd1.z + cc.y + cc.w)
                + cs1 * (vu4.z + vd4.z + l4.z + r4.z)
                + cs2 * (vu16.z + vd16.z + l16.z + r16.z)
                + cu * cc.z + ct0 * p1.z + ct1 * p2.z;
            o.w = cs0 * (vu1.w + vd1.w + cc.z + r4.x)
                + cs1 * (vu4.w + vd4.w + l4.w + r4.w)
                + cs2 * (vu16.w + vd16.w + l16.w + r16.w)
                + cu * cc.w + ct0 * p1.w + ct1 * p2.w;

            __builtin_nontemporal_store(o, &outp[r * 32 + colc]);
        }

        // rotate temporal history
        #pragma unroll
        for (int q = 0; q < 4; ++q) { pm2[q] = pm1[q]; pm1[q] = c0[q]; }
    }
}

extern "C" void kernel_launch(void* const* d_in, const int* in_sizes, int n_in,
                              void* d_out, int out_size, void* d_ws, size_t ws_size,
                              hipStream_t stream) {
    const float* u  = (const float*)d_in[0];
    const float* Ds = (const float*)d_in[1];
    const float* Dt = (const float*)d_in[2];
    float* out = (float*)d_out;

    const int nblocks = BB * CC;   // 256 blocks x 1024 threads = full-plane bands
    lap_st_kernel<<<dim3(nblocks), dim3(1024), 0, stream>>>(u, Ds, Dt, out);
}

// Round 21
// 100.029 us; speedup vs baseline: 1.7617x; 1.7617x over previous
//
#include <hip/hip_runtime.h>
#include <math.h>

// Problem dims (from reference): B=4, C=64, T=16, H=128, W=128, fp32.
#define BB 4
#define CC 64
#define TT 16
#define HH 128
#define WW 128
#define HW (HH*WW)

typedef float f32x4 __attribute__((ext_vector_type(4)));

__device__ __forceinline__ float softplus_f(float x) {
    return (x > 20.0f) ? x : log1pf(expf(x));
}

__device__ __forceinline__ float4 splat4(float v) { return make_float4(v, v, v, v); }

// float4 cross-lane fetch within a 32-lane row segment (ds_bpermute x4).
__device__ __forceinline__ float4 shfl4(float4 v, int src) {
    float4 r;
    r.x = __shfl(v.x, src, 32);
    r.y = __shfl(v.y, src, 32);
    r.z = __shfl(v.z, src, 32);
    r.w = __shfl(v.w, src, 32);
    return r;
}

// FINAL (round-19 config, 99.0us — best of 20 rounds / 11 structural
// variants). 64-row bands: 512 blocks x 512 threads (2 blocks/CU x 8
// waves = 16 waves/CU).
// Band-size series: 32 rows = 101.2us, 64 rows = 99.0us, 128 rows =
// spill-poisoned (1024-thread blocks are VGPR-capped at 64 by the
// compiler in every observed round; this body needs 88).
// Proven-regressing axes (do not revisit):
//  - more TLP: 2x waves/CU inflates FETCH 164->310+ MB (L3 thrash), +35us
//  - any barrier (even lgkm-only): +11..64us bubble, waves must free-run
//  - cross-plane prefetch (regs or DMA/global_load_lds): +10..40us
//  - within-plane load batching: kills compiler interleave, +37us
//  - halo-staging decompositions: pay HBM for overlap, +240us
//  - ",N" launch_bounds: pins VGPR, spills (FETCH ~1GB in worst case)
//  - thread owns 4 stacked rows; d=1 vertical taps from own registers
//  - horizontal taps via lane shuffles (113->101us win at round 11)
//  - temporal history (t-1, t-2) in registers -> temporal taps free
//  - NT stores: output never re-read
//  - bid = sh*256 + bc -> bid%8 == bc%8: a stack's 2 bands share an XCD
__global__ __launch_bounds__(512) void lap_st_kernel(
    const float* __restrict__ u,
    const float* __restrict__ Ds,   // (3, 64)
    const float* __restrict__ Dt,   // (2, 64)
    float* __restrict__ out)
{
    const int bid  = blockIdx.x;
    const int sh   = bid >> 8;             // 0..1 : 64-row band
    const int bc   = bid & 255;            // b*C + c
    const int c    = bc & (CC - 1);
    const int tid  = threadIdx.x;
    const int jj   = tid >> 5;             // 0..15 : row group within band
    const int colc = tid & 31;             // chunk column (lane in row segment)
    const int col  = colc << 2;
    const int r0   = (sh << 6) + (jj << 2); // first of 4 owned rows, 0..124

    const float cs0 = softplus_f(Ds[0 * CC + c]);
    const float cs1 = softplus_f(Ds[1 * CC + c]);
    const float cs2 = softplus_f(Ds[2 * CC + c]);
    const float ct0 = softplus_f(Dt[0 * CC + c]);
    const float ct1 = softplus_f(Dt[1 * CC + c]);
    const float cu = -4.0f * (cs0 + cs1 + cs2) - (ct0 + ct1);

    const size_t bc_off = (size_t)bc * TT * HW;

    float4 pm1[4], pm2[4];

    #pragma unroll 1
    for (int t = 0; t < TT; ++t) {
        const float* __restrict__ up = u + bc_off + (size_t)t * HW;
        f32x4* outp = (f32x4*)(out + bc_off + (size_t)t * HW);

        // center rows (registers; feed +-1 taps, horizontals via shuffle,
        // and the temporal rotate)
        float4 c0[4];
        #pragma unroll
        for (int q = 0; q < 4; ++q)
            c0[q] = *(const float4*)(up + (r0 + q) * WW + col);

        if (t == 0) {   // causal clamp: u[-1] = u[-2] = u[0]
            #pragma unroll
            for (int q = 0; q < 4; ++q) { pm1[q] = c0[q]; pm2[q] = c0[q]; }
        }

        // shared boundary rows (serve +-1 taps of edge q and +-4 taps)
        const int rm1 = (r0 - 1 < 0) ? 0 : r0 - 1;
        const int rp4 = (r0 + 4 > HH - 1) ? HH - 1 : r0 + 4;
        const float4 vm1 = *(const float4*)(up + rm1 * WW + col);
        const float4 vp4 = *(const float4*)(up + rp4 * WW + col);

        #pragma unroll
        for (int q = 0; q < 4; ++q) {
            const int r = r0 + q;

            // ---- vertical taps (register reuse for d=1; clamped loads) ----
            const float4 vu1 = (q == 0) ? vm1 : c0[q - 1];
            const float4 vd1 = (q == 3) ? vp4 : c0[q + 1];
            float4 vu4, vd4;
            if (q == 3) vu4 = vm1;                       // r-4 == r0-1
            else { int rr = r - 4; rr = rr < 0 ? 0 : rr;
                   vu4 = *(const float4*)(up + rr * WW + col); }
            if (q == 0) vd4 = vp4;                       // r+4 == r0+4
            else { int rr = r + 4; rr = rr > HH - 1 ? HH - 1 : rr;
                   vd4 = *(const float4*)(up + rr * WW + col); }
            int ru16 = r - 16; ru16 = ru16 < 0 ? 0 : ru16;
            int rd16 = r + 16; rd16 = rd16 > HH - 1 ? HH - 1 : rd16;
            const float4 vu16 = *(const float4*)(up + ru16 * WW + col);
            const float4 vd16 = *(const float4*)(up + rd16 * WW + col);

            const float4 cc = c0[q];

            // ---- horizontal taps from adjacent lanes' registers ----
            const float4 L4  = shfl4(cc, colc - 1);
            const float4 R4  = shfl4(cc, colc + 1);
            const float4 L16 = shfl4(cc, colc - 4);
            const float4 R16 = shfl4(cc, colc + 4);
            const float e0   = __shfl(cc.x, 0, 32);    // row elem 0
            const float e127 = __shfl(cc.w, 31, 32);   // row elem 127
            const float4 l4  = (colc >= 1)  ? L4  : splat4(e0);
            const float4 r4  = (colc <= 30) ? R4  : splat4(e127);
            const float4 l16 = (colc >= 4)  ? L16 : splat4(e0);
            const float4 r16 = (colc <= 27) ? R16 : splat4(e127);

            const float4 p1 = pm1[q];
            const float4 p2 = pm2[q];

            f32x4 o;
            o.x = cs0 * (vu1.x + vd1.x + l4.w + cc.y)
                + cs1 * (vu4.x + vd4.x + l4.x + r4.x)
                + cs2 * (vu16.x + vd16.x + l16.x + r16.x)
                + cu * cc.x + ct0 * p1.x + ct1 * p2.x;
            o.y = cs0 * (vu1.y + vd1.y + cc.x + cc.z)
                + cs1 * (vu4.y + vd4.y + l4.y + r4.y)
                + cs2 * (vu16.y + vd16.y + l16.y + r16.y)
                + cu * cc.y + ct0 * p1.y + ct1 * p2.y;
            o.z = cs0 * (vu1.z + vd1.z + cc.y + cc.w)
                + cs1 * (vu4.z + vd4.z + l4.z + r4.z)
                + cs2 * (vu16.z + vd16.z + l16.z + r16.z)
                + cu * cc.z + ct0 * p1.z + ct1 * p2.z;
            o.w = cs0 * (vu1.w + vd1.w + cc.z + r4.x)
                + cs1 * (vu4.w + vd4.w + l4.w + r4.w)
                + cs2 * (vu16.w + vd16.w + l16.w + r16.w)
                + cu * cc.w + ct0 * p1.w + ct1 * p2.w;

            __builtin_nontemporal_store(o, &outp[r * 32 + colc]);
        }

        // rotate temporal history
        #pragma unroll
        for (int q = 0; q < 4; ++q) { pm2[q] = pm1[q]; pm1[q] = c0[q]; }
    }
}

extern "C" void kernel_launch(void* const* d_in, const int* in_sizes, int n_in,
                              void* d_out, int out_size, void* d_ws, size_t ws_size,
                              hipStream_t stream) {
    const float* u  = (const float*)d_in[0];
    const float* Ds = (const float*)d_in[1];
    const float* Dt = (const float*)d_in[2];
    float* out = (float*)d_out;

    const int nblocks = 2 * BB * CC;   // 512 blocks x 512 threads = 2 blocks/CU
    lap_st_kernel<<<dim3(nblocks), dim3(512), 0, stream>>>(u, Ds, Dt, out);
}